// Round 5
// baseline (260.953 us; speedup 1.0000x reference)
//
#include <hip/hip_runtime.h>
#include <hip/hip_bf16.h>
#include <cstdint>

#define B_  2
#define S_  2048
#define D_  1024
#define H_  16
#define HD_ 64
#define M_  (B_ * S_)   // 4096
static constexpr float SC_LOG2E = 0.125f * 1.44269504088896f;  // SCALE * log2(e), folded into Q

typedef __bf16 bf16x8 __attribute__((ext_vector_type(8)));
typedef __bf16 bf16x4 __attribute__((ext_vector_type(4)));
typedef float  f32x4  __attribute__((ext_vector_type(4)));

__device__ __forceinline__ unsigned short f2b(float f) {
  union { float f; unsigned u; } x; x.f = f;
  unsigned r = x.u + 0x7FFF + ((x.u >> 16) & 1);   // RNE
  return (unsigned short)(r >> 16);
}

// async global->LDS, 16B per lane; HW uses wave-uniform LDS base + lane*16
__device__ __forceinline__ void gl_lds16(const unsigned short* g, unsigned short* l) {
  __builtin_amdgcn_global_load_lds((const __attribute__((address_space(1))) void*)g,
                                   (__attribute__((address_space(3))) void*)l, 16, 0, 0);
}

// Barriers that do NOT drain vmcnt(0) (unlike __syncthreads) — keep global loads in flight.
__device__ __forceinline__ void bar_lgkm() {
  asm volatile("s_waitcnt lgkmcnt(0)\n\ts_barrier" ::: "memory");
}
__device__ __forceinline__ void bar_vm2() {
  asm volatile("s_waitcnt vmcnt(2) lgkmcnt(0)\n\ts_barrier" ::: "memory");
}
__device__ __forceinline__ void bar_vm0() {
  asm volatile("s_waitcnt vmcnt(0) lgkmcnt(0)\n\ts_barrier" ::: "memory");
}

// ------------------------------------------- fused cvt: z<4 -> transpose+cvt W, z==4 -> cvt x
__global__ void cvt_all_kernel(const float* __restrict__ x,
                               const float* __restrict__ w0, const float* __restrict__ w1,
                               const float* __restrict__ w2, const float* __restrict__ w3,
                               unsigned short* __restrict__ xb,
                               unsigned short* __restrict__ o0, unsigned short* __restrict__ o1,
                               unsigned short* __restrict__ o2, unsigned short* __restrict__ o3) {
  int tx = threadIdx.x, ty = threadIdx.y;
  if (blockIdx.z == 4) {
    int tid = ty * 32 + tx;
    int base = ((int)blockIdx.y * 32 + (int)blockIdx.x) * 1024 + tid;  // f4 index
    const float4* xf = (const float4*)x;
    ushort4* ob = (ushort4*)xb;
#pragma unroll
    for (int j = 0; j < 4; j++) {
      float4 v = xf[base + j * 256];
      ushort4 r;
      r.x = f2b(v.x); r.y = f2b(v.y); r.z = f2b(v.z); r.w = f2b(v.w);
      ob[base + j * 256] = r;
    }
    return;
  }
  const float* w = blockIdx.z == 0 ? w0 : blockIdx.z == 1 ? w1 : blockIdx.z == 2 ? w2 : w3;
  unsigned short* o = blockIdx.z == 0 ? o0 : blockIdx.z == 1 ? o1 : blockIdx.z == 2 ? o2 : o3;
  __shared__ float t[32][33];
  int x0 = blockIdx.x * 32, y0 = blockIdx.y * 32;
#pragma unroll
  for (int j = 0; j < 4; j++)
    t[ty + j * 8][tx] = w[(size_t)(y0 + ty + j * 8) * D_ + x0 + tx];
  __syncthreads();
#pragma unroll
  for (int j = 0; j < 4; j++)
    o[(size_t)(x0 + ty + j * 8) * D_ + y0 + tx] = f2b(t[tx][ty + j * 8]);
}

// ---------------------------------------------------------------- QKV GEMM (unchanged)
__global__ __launch_bounds__(512) void qkv_gemm_kernel(
    const unsigned short* __restrict__ xb,
    const unsigned short* __restrict__ wqt, const unsigned short* __restrict__ wkt,
    const unsigned short* __restrict__ wvt,
    const float* __restrict__ bq, const float* __restrict__ bk, const float* __restrict__ bv,
    unsigned short* __restrict__ qo, unsigned short* __restrict__ ko, unsigned short* __restrict__ vo) {
  const unsigned short* wt = blockIdx.z == 0 ? wqt : blockIdx.z == 1 ? wkt : wvt;
  const float* bias        = blockIdx.z == 0 ? bq  : blockIdx.z == 1 ? bk  : bv;
  unsigned short* out      = blockIdx.z == 0 ? qo  : blockIdx.z == 1 ? ko  : vo;
  const float scl = blockIdx.z == 0 ? SC_LOG2E : 1.0f;

  __shared__ __align__(16) unsigned short smem[6 * 4096];   // 48 KB
  const int tid = threadIdx.x;
  const int lane = tid & 63, wid = tid >> 6;
  const int wm = wid & 1, wn = wid >> 1;
  const int m0 = blockIdx.x * 128, n0 = blockIdx.y * 128;
  const int l15 = lane & 15, q4 = lane >> 4;
  const int srow = tid >> 2, skc = (tid & 3) * 8;

  f32x4 zero = {0.f, 0.f, 0.f, 0.f};
  f32x4 acc[4][2];
#pragma unroll
  for (int mt = 0; mt < 4; mt++)
#pragma unroll
    for (int nt = 0; nt < 2; nt++) acc[mt][nt] = zero;

  const unsigned short* ap = xb + (size_t)(m0 + srow) * D_ + skc;
  const unsigned short* bp = wt + (size_t)(n0 + srow) * D_ + skc;
  gl_lds16(ap,      smem + tid * 8);
  gl_lds16(bp,      smem + 12288 + tid * 8);
  gl_lds16(ap + 32, smem + 4096 + tid * 8);
  gl_lds16(bp + 32, smem + 12288 + 4096 + tid * 8);

  int bc = 0;
  for (int it = 0; it < 32; it++) {
    if (it < 31) bar_vm2(); else bar_vm0();
    if (it + 2 < 32) {
      int bn_ = bc < 1 ? bc + 2 : bc - 1;
      gl_lds16(ap + (it + 2) * 32, smem + bn_ * 4096 + tid * 8);
      gl_lds16(bp + (it + 2) * 32, smem + 12288 + bn_ * 4096 + tid * 8);
    }
    const unsigned short* Ab = smem + bc * 4096;
    const unsigned short* Bb = smem + 12288 + bc * 4096;
    bf16x8 af[4], bfv[2];
#pragma unroll
    for (int mt = 0; mt < 4; mt++) af[mt]  = *(const bf16x8*)(Ab + (wm * 64 + mt * 16 + l15) * 32 + q4 * 8);
#pragma unroll
    for (int nt = 0; nt < 2; nt++) bfv[nt] = *(const bf16x8*)(Bb + (wn * 32 + nt * 16 + l15) * 32 + q4 * 8);
#pragma unroll
    for (int mt = 0; mt < 4; mt++)
#pragma unroll
      for (int nt = 0; nt < 2; nt++)
        acc[mt][nt] = __builtin_amdgcn_mfma_f32_16x16x32_bf16(af[mt], bfv[nt], acc[mt][nt], 0, 0, 0);
    bc = bc == 2 ? 0 : bc + 1;
  }

  if (blockIdx.z < 2) {
#pragma unroll
    for (int nt = 0; nt < 2; nt++) {
      int n = n0 + wn * 32 + nt * 16 + l15;
      float bn = bias[n];
      int h = n >> 6, hd = n & 63;
#pragma unroll
      for (int mt = 0; mt < 4; mt++) {
#pragma unroll
        for (int r = 0; r < 4; r++) {
          int m = m0 + wm * 64 + mt * 16 + q4 * 4 + r;
          int b = m >> 11, s = m & (S_ - 1);
          out[(((size_t)(b * H_ + h)) * S_ + s) * HD_ + hd] = f2b((acc[mt][nt][r] + bn) * scl);
        }
      }
    }
  } else {
    unsigned short* buf = smem;
#pragma unroll
    for (int p = 0; p < 2; p++) {
      __syncthreads();
      if ((wn >> 1) == p) {
#pragma unroll
        for (int nt = 0; nt < 2; nt++) {
          int np = (wn & 1) * 32 + nt * 16 + l15;
          float bn = bias[n0 + p * 64 + np];
#pragma unroll
          for (int mt = 0; mt < 4; mt++) {
            f32x4 vb = acc[mt][nt];
            vb[0] += bn; vb[1] += bn; vb[2] += bn; vb[3] += bn;
            bf16x4 pk = __builtin_convertvector(vb, bf16x4);
            *(bf16x4*)(&buf[np * 136 + wm * 64 + mt * 16 + q4 * 4]) = pk;
          }
        }
      }
      __syncthreads();
#pragma unroll
      for (int i = 0; i < 2; i++) {
        int ci = tid + i * 512;
        int np = ci >> 4, c = ci & 15;
        int n = n0 + p * 64 + np;
        int h = n >> 6, hd = n & 63;
        int m = m0 + c * 8;
        int b = m >> 11, s = m & (S_ - 1);
        *(uint4*)(out + (((size_t)(b * H_ + h)) * HD_ + hd) * S_ + s) = *(const uint4*)(buf + np * 136 + c * 8);
      }
    }
  }
}

// ---------------------------------------------------------------- flash attention v5
// BARRIER-FREE, L2-DIRECT. 1024 blocks x 256 threads (4 waves); 64-row q-tiles,
// 16 q-rows per wave (R3's proven compute core). K/V fragments are read DIRECTLY from
// global: K [S][HD] rows are exactly the QK A-frag layout, Vt [HD][S] rows exactly the
// PV B-frag layout (coalesced 64B..2KB segments). Per-XCD working set = 4 heads x
// (K 256KB + V 256KB) = 2 MB < 4 MB L2 (bh%8 == id%8 clustering) -> re-reads are L2
// hits; staging them through LDS was pure overhead (Common-mistake #7 / m169) and its
// barriers convoyed the waves (R0-R4: every barriered variant stuck at 44-55us).
// No barriers, no staging => 16 fully independent wave-streams per CU (4 blocks x 4
// waves) that the scheduler phase-mixes freely.
// Balance: co-resident qi sets {t8, 15-t8, 16+t8, 31-t8} sum to 62 for every t8 ->
// per-CU work uniform. LDS = 9 KB (P slices only).
__global__ __launch_bounds__(256, 4) void attn_kernel(
    const unsigned short* __restrict__ Q, const unsigned short* __restrict__ K,
    const unsigned short* __restrict__ Vt_g, unsigned short* __restrict__ O) {
  const int id = blockIdx.x;
  const int bh = id & 31;                        // id%8 == bh%8 -> per-head XCD clustering
  const int tIdx = id >> 5;                      // 0..31
  const int u = tIdx >> 3, t8 = tIdx & 7;
  const int qi = (u == 0) ? t8 : (u == 1) ? (15 - t8) : (u == 2) ? (16 + t8) : (31 - t8);
  const int b = bh >> 4, h = bh & 15;
  const unsigned short* Qh = Q    + (size_t)bh * S_ * HD_;
  const unsigned short* Kh = K    + (size_t)bh * S_ * HD_;
  const unsigned short* Vh = Vt_g + (size_t)bh * HD_ * S_;   // [HD][S]

  __shared__ __align__(16) unsigned short Ps[4][16 * 72];    // per-wave P [q][key] 9 KB

  const int tid = threadIdx.x, lane = tid & 63, w = tid >> 6;
  const int l15 = lane & 15, q4 = lane >> 4;
  unsigned short* Pw = &Ps[w][0];

  const int q0 = qi * 64;
  const int nkt = qi + 1;                        // 64-key tiles; last tile is the diagonal
  const int qlo = q0 + w * 16;
  const int qrow = qlo + l15;

  // Q B-frags direct from global (row qrow is exactly the B-frag layout)
  const unsigned short* qp = Qh + (size_t)qrow * HD_ + q4 * 8;
  bf16x8 bq0 = *(const bf16x8*)(qp);
  bf16x8 bq1 = *(const bf16x8*)(qp + 32);

  float m_i = -1e30f, l_i = 0.f;
  f32x4 zero = {0.f, 0.f, 0.f, 0.f};
  f32x4 o_acc[4];
#pragma unroll
  for (int t4 = 0; t4 < 4; t4++) o_acc[t4] = zero;

  for (int kt = 0; kt < nkt; kt++) {
    const int k0 = kt * 64;

    // S^T = K.Q^T : A-frags straight from global K rows (L2-hot)
    f32x4 sc[4];
#pragma unroll
    for (int nt = 0; nt < 4; nt++) sc[nt] = zero;
    __builtin_amdgcn_s_setprio(1);
#pragma unroll
    for (int nt = 0; nt < 4; nt++) {
      const unsigned short* kr = Kh + (size_t)(k0 + nt * 16 + l15) * HD_ + q4 * 8;
      bf16x8 ak0 = *(const bf16x8*)(kr);
      bf16x8 ak1 = *(const bf16x8*)(kr + 32);
      sc[nt] = __builtin_amdgcn_mfma_f32_16x16x32_bf16(ak0, bq0, sc[nt], 0, 0, 0);
      sc[nt] = __builtin_amdgcn_mfma_f32_16x16x32_bf16(ak1, bq1, sc[nt], 0, 0, 0);
    }
    __builtin_amdgcn_s_setprio(0);

    // causal mask — only the diagonal tile (kt == nkt-1) overlaps any wave's rows
    if (k0 + 63 > qlo) {
#pragma unroll
      for (int nt = 0; nt < 4; nt++)
#pragma unroll
        for (int r = 0; r < 4; r++) {
          int key = k0 + nt * 16 + q4 * 4 + r;
          if (key > qrow) sc[nt][r] = -1e30f;
        }
    }

    // tree max
    float am[4];
#pragma unroll
    for (int nt = 0; nt < 4; nt++)
      am[nt] = fmaxf(fmaxf(sc[nt][0], sc[nt][1]), fmaxf(sc[nt][2], sc[nt][3]));
    am[0] = fmaxf(am[0], am[2]); am[1] = fmaxf(am[1], am[3]);
    float mx = fmaxf(am[0], am[1]);
    mx = fmaxf(mx, __shfl_xor(mx, 16));
    mx = fmaxf(mx, __shfl_xor(mx, 32));
    mx = fmaxf(mx, m_i);

    // T13 defer-max: skip O-rescale while tile max grows < 2^10 (log2 domain)
    if (!__all(mx - m_i <= 10.0f)) {
      float alpha = __builtin_amdgcn_exp2f(m_i - mx);
      m_i = mx;
      l_i *= alpha;
#pragma unroll
      for (int r = 0; r < 4; r++) {
        float ar = __shfl(alpha, q4 * 4 + r);
        o_acc[0][r] *= ar; o_acc[1][r] *= ar; o_acc[2][r] *= ar; o_acc[3][r] *= ar;
      }
    }

    // exp2 + tree sum
    float sm[4];
#pragma unroll
    for (int nt = 0; nt < 4; nt++) {
      f32x4 pv;
#pragma unroll
      for (int r = 0; r < 4; r++) pv[r] = __builtin_amdgcn_exp2f(sc[nt][r] - m_i);
      sc[nt] = pv;
      sm[nt] = (pv[0] + pv[1]) + (pv[2] + pv[3]);
    }
    float rs = (sm[0] + sm[2]) + (sm[1] + sm[3]);
    rs += __shfl_xor(rs, 16);
    rs += __shfl_xor(rs, 32);
    l_i += rs;

    // P^T -> Ps[q][key] (wave-local, ONE fence), PV B-frags straight from global Vt rows
#pragma unroll
    for (int nt = 0; nt < 4; nt++) {
      bf16x4 pk = __builtin_convertvector(sc[nt], bf16x4);
      *(bf16x4*)(Pw + l15 * 72 + nt * 16 + q4 * 4) = pk;
    }
    __threadfence_block();                        // wave-local LDS write->read ordering
    bf16x8 ap0 = *(const bf16x8*)(Pw + l15 * 72 + q4 * 8);
    bf16x8 ap1 = *(const bf16x8*)(Pw + l15 * 72 + 32 + q4 * 8);
    __builtin_amdgcn_s_setprio(1);
#pragma unroll
    for (int nt2 = 0; nt2 < 4; nt2++) {
      bf16x8 bv0 = *(const bf16x8*)(Vh + (size_t)(nt2 * 16 + l15) * S_ + k0 + q4 * 8);
      o_acc[nt2] = __builtin_amdgcn_mfma_f32_16x16x32_bf16(ap0, bv0, o_acc[nt2], 0, 0, 0);
    }
#pragma unroll
    for (int nt2 = 0; nt2 < 4; nt2++) {
      bf16x8 bv1 = *(const bf16x8*)(Vh + (size_t)(nt2 * 16 + l15) * S_ + k0 + 32 + q4 * 8);
      o_acc[nt2] = __builtin_amdgcn_mfma_f32_16x16x32_bf16(ap1, bv1, o_acc[nt2], 0, 0, 0);
    }
    __builtin_amdgcn_s_setprio(0);
  }

  // epilogue: O[q=q4*4+r][hd=nt2*16+l15] / l[q] -> bf16 [B,S,D]
#pragma unroll
  for (int r = 0; r < 4; r++) {
    float lr = __shfl(l_i, q4 * 4 + r);
    float inv = 1.0f / lr;
    int s_ = q0 + w * 16 + q4 * 4 + r;
#pragma unroll
    for (int nt2 = 0; nt2 < 4; nt2++)
      O[((size_t)(b * S_ + s_)) * D_ + h * HD_ + nt2 * 16 + l15] = f2b(o_acc[nt2][r] * inv);
  }
}

// ---------------------------------------------------------------- output GEMM (unchanged)
__global__ __launch_bounds__(512) void out_gemm_kernel(
    const unsigned short* __restrict__ ab, const unsigned short* __restrict__ wot,
    const float* __restrict__ bo, float* __restrict__ out) {
  __shared__ __align__(16) unsigned short smem[6 * 4096];   // 48 KB
  const int tid = threadIdx.x;
  const int lane = tid & 63, wid = tid >> 6;
  const int wm = wid & 1, wn = wid >> 1;
  const int m0 = blockIdx.x * 128, n0 = blockIdx.y * 128;
  const int l15 = lane & 15, q4 = lane >> 4;
  const int srow = tid >> 2, skc = (tid & 3) * 8;

  f32x4 zero = {0.f, 0.f, 0.f, 0.f};
  f32x4 acc[4][2];
#pragma unroll
  for (int mt = 0; mt < 4; mt++)
#pragma unroll
    for (int nt = 0; nt < 2; nt++) acc[mt][nt] = zero;

  const unsigned short* ap = ab  + (size_t)(m0 + srow) * D_ + skc;
  const unsigned short* bp = wot + (size_t)(n0 + srow) * D_ + skc;
  gl_lds16(ap,      smem + tid * 8);
  gl_lds16(bp,      smem + 12288 + tid * 8);
  gl_lds16(ap + 32, smem + 4096 + tid * 8);
  gl_lds16(bp + 32, smem + 12288 + 4096 + tid * 8);

  int bc = 0;
  for (int it = 0; it < 32; it++) {
    if (it < 31) bar_vm2(); else bar_vm0();
    if (it + 2 < 32) {
      int bn_ = bc < 1 ? bc + 2 : bc - 1;
      gl_lds16(ap + (it + 2) * 32, smem + bn_ * 4096 + tid * 8);
      gl_lds16(bp + (it + 2) * 32, smem + 12288 + bn_ * 4096 + tid * 8);
    }
    const unsigned short* Ab = smem + bc * 4096;
    const unsigned short* Bb = smem + 12288 + bc * 4096;
    bf16x8 af[4], bfv[2];
#pragma unroll
    for (int mt = 0; mt < 4; mt++) af[mt]  = *(const bf16x8*)(Ab + (wm * 64 + mt * 16 + l15) * 32 + q4 * 8);
#pragma unroll
    for (int nt = 0; nt < 2; nt++) bfv[nt] = *(const bf16x8*)(Bb + (wn * 32 + nt * 16 + l15) * 32 + q4 * 8);
#pragma unroll
    for (int mt = 0; mt < 4; mt++)
#pragma unroll
      for (int nt = 0; nt < 2; nt++)
        acc[mt][nt] = __builtin_amdgcn_mfma_f32_16x16x32_bf16(af[mt], bfv[nt], acc[mt][nt], 0, 0, 0);
    bc = bc == 2 ? 0 : bc + 1;
  }

#pragma unroll
  for (int nt = 0; nt < 2; nt++) {
    int n = n0 + wn * 32 + nt * 16 + l15;
    float bn = bo[n];
#pragma unroll
    for (int mt = 0; mt < 4; mt++) {
#pragma unroll
      for (int r = 0; r < 4; r++) {
        int m = m0 + wm * 64 + mt * 16 + q4 * 4 + r;
        out[(size_t)m * D_ + n] = acc[mt][nt][r] + bn;
      }
    }
  }
}

// ---------------------------------------------------------------- launch
extern "C" void kernel_launch(void* const* d_in, const int* in_sizes, int n_in,
                              void* d_out, int out_size, void* d_ws, size_t ws_size,
                              hipStream_t stream) {
  const float* x  = (const float*)d_in[0];
  const float* wq = (const float*)d_in[1];
  const float* bq = (const float*)d_in[2];
  const float* wk = (const float*)d_in[3];
  const float* bk = (const float*)d_in[4];
  const float* wv = (const float*)d_in[5];
  const float* bv = (const float*)d_in[6];
  const float* wo = (const float*)d_in[7];
  const float* bo = (const float*)d_in[8];
  float* out = (float*)d_out;

  char* ws = (char*)d_ws;
  unsigned short* xb  = (unsigned short*)(ws);               // 8 MB; reused as attn out
  unsigned short* wqt = (unsigned short*)(ws + (8u  << 20));
  unsigned short* wkt = (unsigned short*)(ws + (10u << 20));
  unsigned short* wvt = (unsigned short*)(ws + (12u << 20));
  unsigned short* wot = (unsigned short*)(ws + (14u << 20));
  unsigned short* qb  = (unsigned short*)(ws + (16u << 20)); // [B,H,S,HD] bf16 (pre-scaled)
  unsigned short* kb  = (unsigned short*)(ws + (24u << 20)); // [B,H,S,HD] bf16
  unsigned short* vtg = (unsigned short*)(ws + (32u << 20)); // [B,H,HD,S] bf16 (transposed V)
  unsigned short* ab  = xb;                                  // attention output [B,S,D] bf16

  cvt_all_kernel<<<dim3(32, 32, 5), dim3(32, 8), 0, stream>>>(x, wq, wk, wv, wo, xb, wqt, wkt, wvt, wot);
  qkv_gemm_kernel<<<dim3(32, 8, 3), dim3(512), 0, stream>>>(xb, wqt, wkt, wvt, bq, bk, bv, qb, kb, vtg);
  attn_kernel<<<dim3(1024), dim3(256), 0, stream>>>(qb, kb, vtg, ab);
  out_gemm_kernel<<<dim3(32, 8), dim3(512), 0, stream>>>(ab, wot, bo, out);
}

// Round 6
// 211.497 us; speedup vs baseline: 1.2338x; 1.2338x over previous
//
#include <hip/hip_runtime.h>
#include <hip/hip_bf16.h>
#include <cstdint>

#define B_  2
#define S_  2048
#define D_  1024
#define H_  16
#define HD_ 64
#define M_  (B_ * S_)   // 4096
static constexpr float SC_LOG2E = 0.125f * 1.44269504088896f;  // SCALE * log2(e), folded into Q

typedef __bf16 bf16x8 __attribute__((ext_vector_type(8)));
typedef __bf16 bf16x4 __attribute__((ext_vector_type(4)));
typedef float  f32x4  __attribute__((ext_vector_type(4)));

__device__ __forceinline__ unsigned short f2b(float f) {
  union { float f; unsigned u; } x; x.f = f;
  unsigned r = x.u + 0x7FFF + ((x.u >> 16) & 1);   // RNE
  return (unsigned short)(r >> 16);
}

// async global->LDS, 16B per lane; HW uses wave-uniform LDS base + lane*16
__device__ __forceinline__ void gl_lds16(const unsigned short* g, unsigned short* l) {
  __builtin_amdgcn_global_load_lds((const __attribute__((address_space(1))) void*)g,
                                   (__attribute__((address_space(3))) void*)l, 16, 0, 0);
}

// Barriers that do NOT drain vmcnt(0) (unlike __syncthreads) — keep global loads in flight.
__device__ __forceinline__ void bar_lgkm() {
  asm volatile("s_waitcnt lgkmcnt(0)\n\ts_barrier" ::: "memory");
}
__device__ __forceinline__ void bar_vm2() {
  asm volatile("s_waitcnt vmcnt(2) lgkmcnt(0)\n\ts_barrier" ::: "memory");
}
__device__ __forceinline__ void bar_vm0() {
  asm volatile("s_waitcnt vmcnt(0) lgkmcnt(0)\n\ts_barrier" ::: "memory");
}

// ------------------------------------------- fused cvt: z<4 -> transpose+cvt W, z==4 -> cvt x
__global__ void cvt_all_kernel(const float* __restrict__ x,
                               const float* __restrict__ w0, const float* __restrict__ w1,
                               const float* __restrict__ w2, const float* __restrict__ w3,
                               unsigned short* __restrict__ xb,
                               unsigned short* __restrict__ o0, unsigned short* __restrict__ o1,
                               unsigned short* __restrict__ o2, unsigned short* __restrict__ o3) {
  int tx = threadIdx.x, ty = threadIdx.y;
  if (blockIdx.z == 4) {
    int tid = ty * 32 + tx;
    int base = ((int)blockIdx.y * 32 + (int)blockIdx.x) * 1024 + tid;  // f4 index
    const float4* xf = (const float4*)x;
    ushort4* ob = (ushort4*)xb;
#pragma unroll
    for (int j = 0; j < 4; j++) {
      float4 v = xf[base + j * 256];
      ushort4 r;
      r.x = f2b(v.x); r.y = f2b(v.y); r.z = f2b(v.z); r.w = f2b(v.w);
      ob[base + j * 256] = r;
    }
    return;
  }
  const float* w = blockIdx.z == 0 ? w0 : blockIdx.z == 1 ? w1 : blockIdx.z == 2 ? w2 : w3;
  unsigned short* o = blockIdx.z == 0 ? o0 : blockIdx.z == 1 ? o1 : blockIdx.z == 2 ? o2 : o3;
  __shared__ float t[32][33];
  int x0 = blockIdx.x * 32, y0 = blockIdx.y * 32;
#pragma unroll
  for (int j = 0; j < 4; j++)
    t[ty + j * 8][tx] = w[(size_t)(y0 + ty + j * 8) * D_ + x0 + tx];
  __syncthreads();
#pragma unroll
  for (int j = 0; j < 4; j++)
    o[(size_t)(x0 + ty + j * 8) * D_ + y0 + tx] = f2b(t[tx][ty + j * 8]);
}

// ---------------------------------------------------------------- QKV GEMM (unchanged)
__global__ __launch_bounds__(512) void qkv_gemm_kernel(
    const unsigned short* __restrict__ xb,
    const unsigned short* __restrict__ wqt, const unsigned short* __restrict__ wkt,
    const unsigned short* __restrict__ wvt,
    const float* __restrict__ bq, const float* __restrict__ bk, const float* __restrict__ bv,
    unsigned short* __restrict__ qo, unsigned short* __restrict__ ko, unsigned short* __restrict__ vo) {
  const unsigned short* wt = blockIdx.z == 0 ? wqt : blockIdx.z == 1 ? wkt : wvt;
  const float* bias        = blockIdx.z == 0 ? bq  : blockIdx.z == 1 ? bk  : bv;
  unsigned short* out      = blockIdx.z == 0 ? qo  : blockIdx.z == 1 ? ko  : vo;
  const float scl = blockIdx.z == 0 ? SC_LOG2E : 1.0f;

  __shared__ __align__(16) unsigned short smem[6 * 4096];   // 48 KB
  const int tid = threadIdx.x;
  const int lane = tid & 63, wid = tid >> 6;
  const int wm = wid & 1, wn = wid >> 1;
  const int m0 = blockIdx.x * 128, n0 = blockIdx.y * 128;
  const int l15 = lane & 15, q4 = lane >> 4;
  const int srow = tid >> 2, skc = (tid & 3) * 8;

  f32x4 zero = {0.f, 0.f, 0.f, 0.f};
  f32x4 acc[4][2];
#pragma unroll
  for (int mt = 0; mt < 4; mt++)
#pragma unroll
    for (int nt = 0; nt < 2; nt++) acc[mt][nt] = zero;

  const unsigned short* ap = xb + (size_t)(m0 + srow) * D_ + skc;
  const unsigned short* bp = wt + (size_t)(n0 + srow) * D_ + skc;
  gl_lds16(ap,      smem + tid * 8);
  gl_lds16(bp,      smem + 12288 + tid * 8);
  gl_lds16(ap + 32, smem + 4096 + tid * 8);
  gl_lds16(bp + 32, smem + 12288 + 4096 + tid * 8);

  int bc = 0;
  for (int it = 0; it < 32; it++) {
    if (it < 31) bar_vm2(); else bar_vm0();
    if (it + 2 < 32) {
      int bn_ = bc < 1 ? bc + 2 : bc - 1;
      gl_lds16(ap + (it + 2) * 32, smem + bn_ * 4096 + tid * 8);
      gl_lds16(bp + (it + 2) * 32, smem + 12288 + bn_ * 4096 + tid * 8);
    }
    const unsigned short* Ab = smem + bc * 4096;
    const unsigned short* Bb = smem + 12288 + bc * 4096;
    bf16x8 af[4], bfv[2];
#pragma unroll
    for (int mt = 0; mt < 4; mt++) af[mt]  = *(const bf16x8*)(Ab + (wm * 64 + mt * 16 + l15) * 32 + q4 * 8);
#pragma unroll
    for (int nt = 0; nt < 2; nt++) bfv[nt] = *(const bf16x8*)(Bb + (wn * 32 + nt * 16 + l15) * 32 + q4 * 8);
#pragma unroll
    for (int mt = 0; mt < 4; mt++)
#pragma unroll
      for (int nt = 0; nt < 2; nt++)
        acc[mt][nt] = __builtin_amdgcn_mfma_f32_16x16x32_bf16(af[mt], bfv[nt], acc[mt][nt], 0, 0, 0);
    bc = bc == 2 ? 0 : bc + 1;
  }

  if (blockIdx.z < 2) {
#pragma unroll
    for (int nt = 0; nt < 2; nt++) {
      int n = n0 + wn * 32 + nt * 16 + l15;
      float bn = bias[n];
      int h = n >> 6, hd = n & 63;
#pragma unroll
      for (int mt = 0; mt < 4; mt++) {
#pragma unroll
        for (int r = 0; r < 4; r++) {
          int m = m0 + wm * 64 + mt * 16 + q4 * 4 + r;
          int b = m >> 11, s = m & (S_ - 1);
          out[(((size_t)(b * H_ + h)) * S_ + s) * HD_ + hd] = f2b((acc[mt][nt][r] + bn) * scl);
        }
      }
    }
  } else {
    unsigned short* buf = smem;
#pragma unroll
    for (int p = 0; p < 2; p++) {
      __syncthreads();
      if ((wn >> 1) == p) {
#pragma unroll
        for (int nt = 0; nt < 2; nt++) {
          int np = (wn & 1) * 32 + nt * 16 + l15;
          float bn = bias[n0 + p * 64 + np];
#pragma unroll
          for (int mt = 0; mt < 4; mt++) {
            f32x4 vb = acc[mt][nt];
            vb[0] += bn; vb[1] += bn; vb[2] += bn; vb[3] += bn;
            bf16x4 pk = __builtin_convertvector(vb, bf16x4);
            *(bf16x4*)(&buf[np * 136 + wm * 64 + mt * 16 + q4 * 4]) = pk;
          }
        }
      }
      __syncthreads();
#pragma unroll
      for (int i = 0; i < 2; i++) {
        int ci = tid + i * 512;
        int np = ci >> 4, c = ci & 15;
        int n = n0 + p * 64 + np;
        int h = n >> 6, hd = n & 63;
        int m = m0 + c * 8;
        int b = m >> 11, s = m & (S_ - 1);
        *(uint4*)(out + (((size_t)(b * H_ + h)) * HD_ + hd) * S_ + s) = *(const uint4*)(buf + np * 136 + c * 8);
      }
    }
  }
}

// ---------------------------------------------------------------- flash attention v6
// = R3 (best, 43.8us) with ONE change: V is NOT staged in LDS. The 8 V B-frags per
// wave are loaded DIRECTLY from global (R5-verified addressing), issued at the top of
// the tile body so the ~1-2k cycles of QK+softmax hide the L1/L2 latency; PV consumes
// them. All 8 waves read the same 8KB V tile -> L1-resident (32KB L1) after first touch.
// Removes 8 of 22 LDS b128 ops per wave-step (the dominant cost term) + V staging.
// K stays LDS-staged (QK is immediately after the barrier - no slack to hide latency;
// R5 proved K-from-global fails). LDS 51->34KB.
// 512 blocks x 512 threads (8 waves), 128-row q-tiles, KVBLK=64, heavy-first LPT
// pairing qi(id)+qi(id+256)=15, id%8==bh%8 per-head XCD clustering. 2 blocks/CU.
__global__ __launch_bounds__(512, 4) void attn_kernel(
    const unsigned short* __restrict__ Q, const unsigned short* __restrict__ K,
    const unsigned short* __restrict__ Vt_g, unsigned short* __restrict__ O) {
  const int id = blockIdx.x;
  const int bh = id & 31;                        // id%8 == bh%8 -> per-head XCD clustering
  const int t = id >> 5;
  const int qi = (t < 8) ? (15 - t) : (t - 8);   // heavy-first; pairs sum to 15
  const int b = bh >> 4, h = bh & 15;
  const unsigned short* Qh = Q    + (size_t)bh * S_ * HD_;
  const unsigned short* Kh = K    + (size_t)bh * S_ * HD_;
  const unsigned short* Vh = Vt_g + (size_t)bh * HD_ * S_;   // [HD][S]

  __shared__ __align__(16) unsigned short Ks[2][64 * 64];    // [buf][key][hd^swz]  16 KB
  __shared__ __align__(16) unsigned short Ps[8][16 * 72];    // per-wave P [q][key] 18 KB

  const int tid = threadIdx.x, lane = tid & 63, w = tid >> 6;
  const int l15 = lane & 15, q4 = lane >> 4;
  const int kx = (l15 & 7) << 3;                 // frag-read XOR (constant per thread)
  const int kcA = (q4 * 8) ^ kx, kcB = (q4 * 8 + 32) ^ kx;
  unsigned short* Pw = &Ps[w][0];

  // K staging: 512 threads x 16B = 8KB tile; write-addr swizzled, read un-swizzles
  const int srow = tid >> 3;                                  // 0..63
  const int scolS = (((tid & 7) ^ (srow & 7)) * 8);           // swizzled LDS col (shorts)
  const unsigned short* kg = Kh + (size_t)srow * HD_ + (tid & 7) * 8;  // + kt*64*HD_

  const int q0 = qi * 128;
  const int nkt = 2 * qi + 2;                    // 64-key tiles covering rows q0..q0+127
  const int qlo = q0 + w * 16;
  const int qmax = qlo + 15;
  const int qrow = qlo + l15;

  // Q B-frags direct from global
  const unsigned short* qp = Qh + (size_t)qrow * HD_ + q4 * 8;
  bf16x8 bq0 = *(const bf16x8*)(qp);
  bf16x8 bq1 = *(const bf16x8*)(qp + 32);

  float m_i = -1e30f, l_i = 0.f;
  f32x4 zero = {0.f, 0.f, 0.f, 0.f};
  f32x4 o_acc[4];
#pragma unroll
  for (int t4 = 0; t4 < 4; t4++) o_acc[t4] = zero;

  // prefetch K tile 0 into reg
  uint4 kp = *(const uint4*)(kg);

  for (int kt = 0; kt < nkt; kt++) {
    const int k0 = kt * 64;
    unsigned short* Kb = Ks[kt & 1];
    *(uint4*)(Kb + srow * 64 + scolS) = kp;      // swizzled ds_write staging
    bar_lgkm();                                  // barrier WITHOUT vmcnt drain
    if (kt + 1 < nkt)                            // prefetch next K tile (flies over compute)
      kp = *(const uint4*)(kg + (size_t)(kt + 1) * 64 * HD_);

    if (k0 <= qmax) {                            // skip fully-masked tiles (wave-uniform)
      // V B-frags from GLOBAL, issued early: latency hides under QK + softmax.
      bf16x8 vfa[4], vfb[4];
#pragma unroll
      for (int nt2 = 0; nt2 < 4; nt2++) {
        const unsigned short* vr = Vh + (size_t)(nt2 * 16 + l15) * S_ + k0 + q4 * 8;
        vfa[nt2] = *(const bf16x8*)(vr);
        vfb[nt2] = *(const bf16x8*)(vr + 32);
      }

      // S^T = K.Q^T : A = K-frag (m=key), B = Q-frag (n=q); Q pre-scaled by SC_LOG2E
      f32x4 sc[4];
#pragma unroll
      for (int nt = 0; nt < 4; nt++) sc[nt] = zero;
      __builtin_amdgcn_s_setprio(1);
#pragma unroll
      for (int nt = 0; nt < 4; nt++) {
        bf16x8 ak0 = *(const bf16x8*)(Kb + (nt * 16 + l15) * 64 + kcA);
        bf16x8 ak1 = *(const bf16x8*)(Kb + (nt * 16 + l15) * 64 + kcB);
        sc[nt] = __builtin_amdgcn_mfma_f32_16x16x32_bf16(ak0, bq0, sc[nt], 0, 0, 0);
        sc[nt] = __builtin_amdgcn_mfma_f32_16x16x32_bf16(ak1, bq1, sc[nt], 0, 0, 0);
      }
      __builtin_amdgcn_s_setprio(0);

      // causal mask (tiles overlapping the diagonal only)
      if ((k0 + 63) > qlo) {
#pragma unroll
        for (int nt = 0; nt < 4; nt++)
#pragma unroll
          for (int r = 0; r < 4; r++) {
            int key = k0 + nt * 16 + q4 * 4 + r;
            if (key > qrow) sc[nt][r] = -1e30f;
          }
      }

      // tree max
      float am[4];
#pragma unroll
      for (int nt = 0; nt < 4; nt++)
        am[nt] = fmaxf(fmaxf(sc[nt][0], sc[nt][1]), fmaxf(sc[nt][2], sc[nt][3]));
      am[0] = fmaxf(am[0], am[2]); am[1] = fmaxf(am[1], am[3]);
      float mx = fmaxf(am[0], am[1]);
      mx = fmaxf(mx, __shfl_xor(mx, 16));
      mx = fmaxf(mx, __shfl_xor(mx, 32));
      mx = fmaxf(mx, m_i);

      // T13 defer-max: skip O-rescale while tile max grows < 2^10 (log2 domain)
      if (!__all(mx - m_i <= 10.0f)) {
        float alpha = __builtin_amdgcn_exp2f(m_i - mx);
        m_i = mx;
        l_i *= alpha;
#pragma unroll
        for (int r = 0; r < 4; r++) {
          float ar = __shfl(alpha, q4 * 4 + r);
          o_acc[0][r] *= ar; o_acc[1][r] *= ar; o_acc[2][r] *= ar; o_acc[3][r] *= ar;
        }
      }

      // exp2 + tree sum
      float sm[4];
#pragma unroll
      for (int nt = 0; nt < 4; nt++) {
        f32x4 pv;
#pragma unroll
        for (int r = 0; r < 4; r++) pv[r] = __builtin_amdgcn_exp2f(sc[nt][r] - m_i);
        sc[nt] = pv;
        sm[nt] = (pv[0] + pv[1]) + (pv[2] + pv[3]);
      }
      float rs = (sm[0] + sm[2]) + (sm[1] + sm[3]);
      rs += __shfl_xor(rs, 16);
      rs += __shfl_xor(rs, 32);
      l_i += rs;

      // P^T -> Ps[q][key] (wave-local, ONE fence), then PV from register V-frags
#pragma unroll
      for (int nt = 0; nt < 4; nt++) {
        bf16x4 pk = __builtin_convertvector(sc[nt], bf16x4);
        *(bf16x4*)(Pw + l15 * 72 + nt * 16 + q4 * 4) = pk;
      }
      __threadfence_block();                      // wave-local LDS write->read ordering
      bf16x8 ap0 = *(const bf16x8*)(Pw + l15 * 72 + q4 * 8);
      bf16x8 ap1 = *(const bf16x8*)(Pw + l15 * 72 + 32 + q4 * 8);
      __builtin_amdgcn_s_setprio(1);
#pragma unroll
      for (int nt2 = 0; nt2 < 4; nt2++)
        o_acc[nt2] = __builtin_amdgcn_mfma_f32_16x16x32_bf16(ap0, vfa[nt2], o_acc[nt2], 0, 0, 0);
#pragma unroll
      for (int nt2 = 0; nt2 < 4; nt2++)
        o_acc[nt2] = __builtin_amdgcn_mfma_f32_16x16x32_bf16(ap1, vfb[nt2], o_acc[nt2], 0, 0, 0);
      __builtin_amdgcn_s_setprio(0);
    }
  }

  // epilogue: O[q=q4*4+r][hd=nt2*16+l15] / l[q] -> bf16 [B,S,D]
#pragma unroll
  for (int r = 0; r < 4; r++) {
    float lr = __shfl(l_i, q4 * 4 + r);
    float inv = 1.0f / lr;
    int s_ = q0 + w * 16 + q4 * 4 + r;
#pragma unroll
    for (int nt2 = 0; nt2 < 4; nt2++)
      O[((size_t)(b * S_ + s_)) * D_ + h * HD_ + nt2 * 16 + l15] = f2b(o_acc[nt2][r] * inv);
  }
}

// ---------------------------------------------------------------- output GEMM (unchanged)
__global__ __launch_bounds__(512) void out_gemm_kernel(
    const unsigned short* __restrict__ ab, const unsigned short* __restrict__ wot,
    const float* __restrict__ bo, float* __restrict__ out) {
  __shared__ __align__(16) unsigned short smem[6 * 4096];   // 48 KB
  const int tid = threadIdx.x;
  const int lane = tid & 63, wid = tid >> 6;
  const int wm = wid & 1, wn = wid >> 1;
  const int m0 = blockIdx.x * 128, n0 = blockIdx.y * 128;
  const int l15 = lane & 15, q4 = lane >> 4;
  const int srow = tid >> 2, skc = (tid & 3) * 8;

  f32x4 zero = {0.f, 0.f, 0.f, 0.f};
  f32x4 acc[4][2];
#pragma unroll
  for (int mt = 0; mt < 4; mt++)
#pragma unroll
    for (int nt = 0; nt < 2; nt++) acc[mt][nt] = zero;

  const unsigned short* ap = ab  + (size_t)(m0 + srow) * D_ + skc;
  const unsigned short* bp = wot + (size_t)(n0 + srow) * D_ + skc;
  gl_lds16(ap,      smem + tid * 8);
  gl_lds16(bp,      smem + 12288 + tid * 8);
  gl_lds16(ap + 32, smem + 4096 + tid * 8);
  gl_lds16(bp + 32, smem + 12288 + 4096 + tid * 8);

  int bc = 0;
  for (int it = 0; it < 32; it++) {
    if (it < 31) bar_vm2(); else bar_vm0();
    if (it + 2 < 32) {
      int bn_ = bc < 1 ? bc + 2 : bc - 1;
      gl_lds16(ap + (it + 2) * 32, smem + bn_ * 4096 + tid * 8);
      gl_lds16(bp + (it + 2) * 32, smem + 12288 + bn_ * 4096 + tid * 8);
    }
    const unsigned short* Ab = smem + bc * 4096;
    const unsigned short* Bb = smem + 12288 + bc * 4096;
    bf16x8 af[4], bfv[2];
#pragma unroll
    for (int mt = 0; mt < 4; mt++) af[mt]  = *(const bf16x8*)(Ab + (wm * 64 + mt * 16 + l15) * 32 + q4 * 8);
#pragma unroll
    for (int nt = 0; nt < 2; nt++) bfv[nt] = *(const bf16x8*)(Bb + (wn * 32 + nt * 16 + l15) * 32 + q4 * 8);
#pragma unroll
    for (int mt = 0; mt < 4; mt++)
#pragma unroll
      for (int nt = 0; nt < 2; nt++)
        acc[mt][nt] = __builtin_amdgcn_mfma_f32_16x16x32_bf16(af[mt], bfv[nt], acc[mt][nt], 0, 0, 0);
    bc = bc == 2 ? 0 : bc + 1;
  }

#pragma unroll
  for (int nt = 0; nt < 2; nt++) {
    int n = n0 + wn * 32 + nt * 16 + l15;
    float bn = bo[n];
#pragma unroll
    for (int mt = 0; mt < 4; mt++) {
#pragma unroll
      for (int r = 0; r < 4; r++) {
        int m = m0 + wm * 64 + mt * 16 + q4 * 4 + r;
        out[(size_t)m * D_ + n] = acc[mt][nt][r] + bn;
      }
    }
  }
}

// ---------------------------------------------------------------- launch
extern "C" void kernel_launch(void* const* d_in, const int* in_sizes, int n_in,
                              void* d_out, int out_size, void* d_ws, size_t ws_size,
                              hipStream_t stream) {
  const float* x  = (const float*)d_in[0];
  const float* wq = (const float*)d_in[1];
  const float* bq = (const float*)d_in[2];
  const float* wk = (const float*)d_in[3];
  const float* bk = (const float*)d_in[4];
  const float* wv = (const float*)d_in[5];
  const float* bv = (const float*)d_in[6];
  const float* wo = (const float*)d_in[7];
  const float* bo = (const float*)d_in[8];
  float* out = (float*)d_out;

  char* ws = (char*)d_ws;
  unsigned short* xb  = (unsigned short*)(ws);               // 8 MB; reused as attn out
  unsigned short* wqt = (unsigned short*)(ws + (8u  << 20));
  unsigned short* wkt = (unsigned short*)(ws + (10u << 20));
  unsigned short* wvt = (unsigned short*)(ws + (12u << 20));
  unsigned short* wot = (unsigned short*)(ws + (14u << 20));
  unsigned short* qb  = (unsigned short*)(ws + (16u << 20)); // [B,H,S,HD] bf16 (pre-scaled)
  unsigned short* kb  = (unsigned short*)(ws + (24u << 20)); // [B,H,S,HD] bf16
  unsigned short* vtg = (unsigned short*)(ws + (32u << 20)); // [B,H,HD,S] bf16 (transposed V)
  unsigned short* ab  = xb;                                  // attention output [B,S,D] bf16

  cvt_all_kernel<<<dim3(32, 32, 5), dim3(32, 8), 0, stream>>>(x, wq, wk, wv, wo, xb, wqt, wkt, wvt, wot);
  qkv_gemm_kernel<<<dim3(32, 8, 3), dim3(512), 0, stream>>>(xb, wqt, wkt, wvt, bq, bk, bv, qb, kb, vtg);
  attn_kernel<<<dim3(512), dim3(512), 0, stream>>>(qb, kb, vtg, ab);
  out_gemm_kernel<<<dim3(32, 8), dim3(512), 0, stream>>>(ab, wot, bo, out);
}

// Round 7
// 181.540 us; speedup vs baseline: 1.4374x; 1.1650x over previous
//
#include <hip/hip_runtime.h>
#include <hip/hip_bf16.h>
#include <cstdint>

#define B_  2
#define S_  2048
#define D_  1024
#define H_  16
#define HD_ 64
#define M_  (B_ * S_)   // 4096
static constexpr float SC_LOG2E = 0.125f * 1.44269504088896f;  // SCALE * log2(e), folded into Q

typedef __bf16 bf16x8 __attribute__((ext_vector_type(8)));
typedef __bf16 bf16x4 __attribute__((ext_vector_type(4)));
typedef float  f32x4  __attribute__((ext_vector_type(4)));

// partial-buffer geometry: 256 (bh,j) pairs x 2 splits x 512 threads, 18 fp32 planes
#define PPLANE (256 * 2 * 512)

__device__ __forceinline__ unsigned short f2b(float f) {
  union { float f; unsigned u; } x; x.f = f;
  unsigned r = x.u + 0x7FFF + ((x.u >> 16) & 1);   // RNE
  return (unsigned short)(r >> 16);
}

// async global->LDS, 16B per lane; HW uses wave-uniform LDS base + lane*16
__device__ __forceinline__ void gl_lds16(const unsigned short* g, unsigned short* l) {
  __builtin_amdgcn_global_load_lds((const __attribute__((address_space(1))) void*)g,
                                   (__attribute__((address_space(3))) void*)l, 16, 0, 0);
}

// Barriers that do NOT drain vmcnt(0) (unlike __syncthreads) — keep global loads in flight.
__device__ __forceinline__ void bar_lgkm() {
  asm volatile("s_waitcnt lgkmcnt(0)\n\ts_barrier" ::: "memory");
}
__device__ __forceinline__ void bar_vm2() {
  asm volatile("s_waitcnt vmcnt(2) lgkmcnt(0)\n\ts_barrier" ::: "memory");
}
__device__ __forceinline__ void bar_vm0() {
  asm volatile("s_waitcnt vmcnt(0) lgkmcnt(0)\n\ts_barrier" ::: "memory");
}

// ------------------------------------------- fused cvt: z<4 -> transpose+cvt W, z==4 -> cvt x
__global__ void cvt_all_kernel(const float* __restrict__ x,
                               const float* __restrict__ w0, const float* __restrict__ w1,
                               const float* __restrict__ w2, const float* __restrict__ w3,
                               unsigned short* __restrict__ xb,
                               unsigned short* __restrict__ o0, unsigned short* __restrict__ o1,
                               unsigned short* __restrict__ o2, unsigned short* __restrict__ o3) {
  int tx = threadIdx.x, ty = threadIdx.y;
  if (blockIdx.z == 4) {
    int tid = ty * 32 + tx;
    int base = ((int)blockIdx.y * 32 + (int)blockIdx.x) * 1024 + tid;  // f4 index
    const float4* xf = (const float4*)x;
    ushort4* ob = (ushort4*)xb;
#pragma unroll
    for (int j = 0; j < 4; j++) {
      float4 v = xf[base + j * 256];
      ushort4 r;
      r.x = f2b(v.x); r.y = f2b(v.y); r.z = f2b(v.z); r.w = f2b(v.w);
      ob[base + j * 256] = r;
    }
    return;
  }
  const float* w = blockIdx.z == 0 ? w0 : blockIdx.z == 1 ? w1 : blockIdx.z == 2 ? w2 : w3;
  unsigned short* o = blockIdx.z == 0 ? o0 : blockIdx.z == 1 ? o1 : blockIdx.z == 2 ? o2 : o3;
  __shared__ float t[32][33];
  int x0 = blockIdx.x * 32, y0 = blockIdx.y * 32;
#pragma unroll
  for (int j = 0; j < 4; j++)
    t[ty + j * 8][tx] = w[(size_t)(y0 + ty + j * 8) * D_ + x0 + tx];
  __syncthreads();
#pragma unroll
  for (int j = 0; j < 4; j++)
    o[(size_t)(x0 + ty + j * 8) * D_ + y0 + tx] = f2b(t[tx][ty + j * 8]);
}

// ---------------------------------------------------------------- QKV GEMM (unchanged)
__global__ __launch_bounds__(512) void qkv_gemm_kernel(
    const unsigned short* __restrict__ xb,
    const unsigned short* __restrict__ wqt, const unsigned short* __restrict__ wkt,
    const unsigned short* __restrict__ wvt,
    const float* __restrict__ bq, const float* __restrict__ bk, const float* __restrict__ bv,
    unsigned short* __restrict__ qo, unsigned short* __restrict__ ko, unsigned short* __restrict__ vo) {
  const unsigned short* wt = blockIdx.z == 0 ? wqt : blockIdx.z == 1 ? wkt : wvt;
  const float* bias        = blockIdx.z == 0 ? bq  : blockIdx.z == 1 ? bk  : bv;
  unsigned short* out      = blockIdx.z == 0 ? qo  : blockIdx.z == 1 ? ko  : vo;
  const float scl = blockIdx.z == 0 ? SC_LOG2E : 1.0f;

  __shared__ __align__(16) unsigned short smem[6 * 4096];   // 48 KB
  const int tid = threadIdx.x;
  const int lane = tid & 63, wid = tid >> 6;
  const int wm = wid & 1, wn = wid >> 1;
  const int m0 = blockIdx.x * 128, n0 = blockIdx.y * 128;
  const int l15 = lane & 15, q4 = lane >> 4;
  const int srow = tid >> 2, skc = (tid & 3) * 8;

  f32x4 zero = {0.f, 0.f, 0.f, 0.f};
  f32x4 acc[4][2];
#pragma unroll
  for (int mt = 0; mt < 4; mt++)
#pragma unroll
    for (int nt = 0; nt < 2; nt++) acc[mt][nt] = zero;

  const unsigned short* ap = xb + (size_t)(m0 + srow) * D_ + skc;
  const unsigned short* bp = wt + (size_t)(n0 + srow) * D_ + skc;
  gl_lds16(ap,      smem + tid * 8);
  gl_lds16(bp,      smem + 12288 + tid * 8);
  gl_lds16(ap + 32, smem + 4096 + tid * 8);
  gl_lds16(bp + 32, smem + 12288 + 4096 + tid * 8);

  int bc = 0;
  for (int it = 0; it < 32; it++) {
    if (it < 31) bar_vm2(); else bar_vm0();
    if (it + 2 < 32) {
      int bn_ = bc < 1 ? bc + 2 : bc - 1;
      gl_lds16(ap + (it + 2) * 32, smem + bn_ * 4096 + tid * 8);
      gl_lds16(bp + (it + 2) * 32, smem + 12288 + bn_ * 4096 + tid * 8);
    }
    const unsigned short* Ab = smem + bc * 4096;
    const unsigned short* Bb = smem + 12288 + bc * 4096;
    bf16x8 af[4], bfv[2];
#pragma unroll
    for (int mt = 0; mt < 4; mt++) af[mt]  = *(const bf16x8*)(Ab + (wm * 64 + mt * 16 + l15) * 32 + q4 * 8);
#pragma unroll
    for (int nt = 0; nt < 2; nt++) bfv[nt] = *(const bf16x8*)(Bb + (wn * 32 + nt * 16 + l15) * 32 + q4 * 8);
#pragma unroll
    for (int mt = 0; mt < 4; mt++)
#pragma unroll
      for (int nt = 0; nt < 2; nt++)
        acc[mt][nt] = __builtin_amdgcn_mfma_f32_16x16x32_bf16(af[mt], bfv[nt], acc[mt][nt], 0, 0, 0);
    bc = bc == 2 ? 0 : bc + 1;
  }

  if (blockIdx.z < 2) {
#pragma unroll
    for (int nt = 0; nt < 2; nt++) {
      int n = n0 + wn * 32 + nt * 16 + l15;
      float bn = bias[n];
      int h = n >> 6, hd = n & 63;
#pragma unroll
      for (int mt = 0; mt < 4; mt++) {
#pragma unroll
        for (int r = 0; r < 4; r++) {
          int m = m0 + wm * 64 + mt * 16 + q4 * 4 + r;
          int b = m >> 11, s = m & (S_ - 1);
          out[(((size_t)(b * H_ + h)) * S_ + s) * HD_ + hd] = f2b((acc[mt][nt][r] + bn) * scl);
        }
      }
    }
  } else {
    unsigned short* buf = smem;
#pragma unroll
    for (int p = 0; p < 2; p++) {
      __syncthreads();
      if ((wn >> 1) == p) {
#pragma unroll
        for (int nt = 0; nt < 2; nt++) {
          int np = (wn & 1) * 32 + nt * 16 + l15;
          float bn = bias[n0 + p * 64 + np];
#pragma unroll
          for (int mt = 0; mt < 4; mt++) {
            f32x4 vb = acc[mt][nt];
            vb[0] += bn; vb[1] += bn; vb[2] += bn; vb[3] += bn;
            bf16x4 pk = __builtin_convertvector(vb, bf16x4);
            *(bf16x4*)(&buf[np * 136 + wm * 64 + mt * 16 + q4 * 4]) = pk;
          }
        }
      }
      __syncthreads();
#pragma unroll
      for (int i = 0; i < 2; i++) {
        int ci = tid + i * 512;
        int np = ci >> 4, c = ci & 15;
        int n = n0 + p * 64 + np;
        int h = n >> 6, hd = n & 63;
        int m = m0 + c * 8;
        int b = m >> 11, s = m & (S_ - 1);
        *(uint4*)(out + (((size_t)(b * H_ + h)) * HD_ + hd) * S_ + s) = *(const uint4*)(buf + np * 136 + c * 8);
      }
    }
  }
}

// ---------------------------------------------------------------- flash attention v7
// R3 core (best verified: 43.8us) + SPLIT-K for the heavy causal half.
// 768 blocks x 512 threads (8 waves), 3 blocks/CU (LDS 3x50KB=150<=160KB, lb(512,6)).
// id decode: g=id&255, r=id>>8; bh=g&31 (id%8==bh%8 XCD clustering), j=g>>5 (0..7).
//   r<2 : HEAVY qi=15-j, split=r: process k-tiles kt=2s+split, s in [0, qi+1)
//         -> write fp32 partials (o_acc, m, l) to workspace; merged by attn_merge.
//   r==2: LIGHT qi=j: whole row block (nst=2qi+2), normal epilogue.
// Per-CU composition {split0,split1,light}: (16-j)+(16-j)+(2j+2)=34 steps on EVERY CU;
// critical chain 32 -> 17 steps; the two 16-step chains phase-mix on 24 waves/CU.
// Per step (R3 verbatim): reg-prefetch K,V -> swizzled ds_write -> bar_lgkm -> QK ->
// softmax (tree + defer-max) -> P->LDS (1 fence) -> PV. Wave-skip of masked tiles.
__global__ __launch_bounds__(512, 6) void attn_kernel(
    const unsigned short* __restrict__ Q, const unsigned short* __restrict__ K,
    const unsigned short* __restrict__ Vt_g, unsigned short* __restrict__ O,
    float* __restrict__ part) {
  const int id = blockIdx.x;
  const int g = id & 255, r = id >> 8;
  const int bh = g & 31, j = g >> 5;
  const bool heavy = (r < 2);
  const int qi = heavy ? (15 - j) : j;
  const int split = heavy ? r : 0;
  const int b = bh >> 4, h = bh & 15;
  const unsigned short* Qh = Q    + (size_t)bh * S_ * HD_;
  const unsigned short* Kh = K    + (size_t)bh * S_ * HD_;
  const unsigned short* Vh = Vt_g + (size_t)bh * HD_ * S_;   // [HD][S]

  __shared__ __align__(16) unsigned short Ks[2][64 * 64];    // [buf][key][hd^swz]  16 KB
  __shared__ __align__(16) unsigned short Vt[2][64 * 64];    // [buf][hd][key^swz]  16 KB
  __shared__ __align__(16) unsigned short Ps[8][16 * 72];    // per-wave P [q][key] 18 KB

  const int tid = threadIdx.x, lane = tid & 63, w = tid >> 6;
  const int l15 = lane & 15, q4 = lane >> 4;
  const int kx = (l15 & 7) << 3;                 // frag-read XOR (constant per thread)
  const int kcA = (q4 * 8) ^ kx, kcB = (q4 * 8 + 32) ^ kx;
  const int vc0 = (q4 * 8) ^ kx, vc1 = (32 + q4 * 8) ^ kx;
  unsigned short* Pw = &Ps[w][0];

  // staging: 512 threads x 16B = 8KB per array per tile (1 uint4 each)
  const int srow = tid >> 3;                                  // 0..63
  const int scolS = (((tid & 7) ^ (srow & 7)) * 8);           // swizzled LDS col (shorts)
  const unsigned short* kg = Kh + (size_t)srow * HD_ + (tid & 7) * 8;  // + kt*64*HD_
  const unsigned short* vg = Vh + (size_t)srow * S_  + (tid & 7) * 8;  // + kt*64

  const int q0 = qi * 128;
  const int nst = heavy ? (qi + 1) : (2 * qi + 2);  // steps this block executes
  const int kstep = heavy ? 2 : 1;
  const int qlo = q0 + w * 16;
  const int qmax = qlo + 15;
  const int qrow = qlo + l15;

  // Q B-frags direct from global
  const unsigned short* qp = Qh + (size_t)qrow * HD_ + q4 * 8;
  bf16x8 bq0 = *(const bf16x8*)(qp);
  bf16x8 bq1 = *(const bf16x8*)(qp + 32);

  float m_i = -1e30f, l_i = 0.f;
  f32x4 zero = {0.f, 0.f, 0.f, 0.f};
  f32x4 o_acc[4];
#pragma unroll
  for (int t4 = 0; t4 < 4; t4++) o_acc[t4] = zero;

  // prefetch first tile (kt0 = split for heavy, 0 for light)
  uint4 kp = *(const uint4*)(kg + (size_t)split * 64 * HD_);
  uint4 vp = *(const uint4*)(vg + split * 64);

  for (int s = 0; s < nst; s++) {
    const int kt = kstep * s + split;
    const int k0 = kt * 64;
    unsigned short* Kb = Ks[s & 1];
    unsigned short* Vb = Vt[s & 1];
    *(uint4*)(Kb + srow * 64 + scolS) = kp;      // swizzled ds_write staging
    *(uint4*)(Vb + srow * 64 + scolS) = vp;
    bar_lgkm();                                  // barrier WITHOUT vmcnt drain
    if (s + 1 < nst) {                           // prefetch next tile (flies over compute)
      const int ktn = kt + kstep;
      kp = *(const uint4*)(kg + (size_t)ktn * 64 * HD_);
      vp = *(const uint4*)(vg + ktn * 64);
    }

    if (k0 <= qmax) {                            // skip fully-masked tiles (wave-uniform)
      // S^T = K.Q^T : A = K-frag (m=key), B = Q-frag (n=q); Q pre-scaled by SC_LOG2E
      f32x4 sc[4];
#pragma unroll
      for (int nt = 0; nt < 4; nt++) sc[nt] = zero;
      __builtin_amdgcn_s_setprio(1);
#pragma unroll
      for (int nt = 0; nt < 4; nt++) {
        bf16x8 ak0 = *(const bf16x8*)(Kb + (nt * 16 + l15) * 64 + kcA);
        bf16x8 ak1 = *(const bf16x8*)(Kb + (nt * 16 + l15) * 64 + kcB);
        sc[nt] = __builtin_amdgcn_mfma_f32_16x16x32_bf16(ak0, bq0, sc[nt], 0, 0, 0);
        sc[nt] = __builtin_amdgcn_mfma_f32_16x16x32_bf16(ak1, bq1, sc[nt], 0, 0, 0);
      }
      __builtin_amdgcn_s_setprio(0);

      // causal mask (tiles overlapping the diagonal only)
      if ((k0 + 63) > qlo) {
#pragma unroll
        for (int nt = 0; nt < 4; nt++)
#pragma unroll
          for (int r2 = 0; r2 < 4; r2++) {
            int key = k0 + nt * 16 + q4 * 4 + r2;
            if (key > qrow) sc[nt][r2] = -1e30f;
          }
      }

      // tree max
      float am[4];
#pragma unroll
      for (int nt = 0; nt < 4; nt++)
        am[nt] = fmaxf(fmaxf(sc[nt][0], sc[nt][1]), fmaxf(sc[nt][2], sc[nt][3]));
      am[0] = fmaxf(am[0], am[2]); am[1] = fmaxf(am[1], am[3]);
      float mx = fmaxf(am[0], am[1]);
      mx = fmaxf(mx, __shfl_xor(mx, 16));
      mx = fmaxf(mx, __shfl_xor(mx, 32));
      mx = fmaxf(mx, m_i);

      // T13 defer-max: skip O-rescale while tile max grows < 2^10 (log2 domain)
      if (!__all(mx - m_i <= 10.0f)) {
        float alpha = __builtin_amdgcn_exp2f(m_i - mx);
        m_i = mx;
        l_i *= alpha;
#pragma unroll
        for (int r2 = 0; r2 < 4; r2++) {
          float ar = __shfl(alpha, q4 * 4 + r2);
          o_acc[0][r2] *= ar; o_acc[1][r2] *= ar; o_acc[2][r2] *= ar; o_acc[3][r2] *= ar;
        }
      }

      // exp2 + tree sum
      float sm[4];
#pragma unroll
      for (int nt = 0; nt < 4; nt++) {
        f32x4 pv;
#pragma unroll
        for (int r2 = 0; r2 < 4; r2++) pv[r2] = __builtin_amdgcn_exp2f(sc[nt][r2] - m_i);
        sc[nt] = pv;
        sm[nt] = (pv[0] + pv[1]) + (pv[2] + pv[3]);
      }
      float rs = (sm[0] + sm[2]) + (sm[1] + sm[3]);
      rs += __shfl_xor(rs, 16);
      rs += __shfl_xor(rs, 32);
      l_i += rs;

      // P^T -> Ps[q][key] (wave-local, ONE fence), then PV with reads pipelined
#pragma unroll
      for (int nt = 0; nt < 4; nt++) {
        bf16x4 pk = __builtin_convertvector(sc[nt], bf16x4);
        *(bf16x4*)(Pw + l15 * 72 + nt * 16 + q4 * 4) = pk;
      }
      __threadfence_block();                      // wave-local LDS write->read ordering
      bf16x8 ap0 = *(const bf16x8*)(Pw + l15 * 72 + q4 * 8);
      bf16x8 ap1 = *(const bf16x8*)(Pw + l15 * 72 + 32 + q4 * 8);
      __builtin_amdgcn_s_setprio(1);
#pragma unroll
      for (int nt2 = 0; nt2 < 4; nt2++) {
        bf16x8 bv0 = *(const bf16x8*)(Vb + (nt2 * 16 + l15) * 64 + vc0);
        o_acc[nt2] = __builtin_amdgcn_mfma_f32_16x16x32_bf16(ap0, bv0, o_acc[nt2], 0, 0, 0);
      }
#pragma unroll
      for (int nt2 = 0; nt2 < 4; nt2++) {
        bf16x8 bv1 = *(const bf16x8*)(Vb + (nt2 * 16 + l15) * 64 + vc1);
        o_acc[nt2] = __builtin_amdgcn_mfma_f32_16x16x32_bf16(ap1, bv1, o_acc[nt2], 0, 0, 0);
      }
      __builtin_amdgcn_s_setprio(0);
    }
  }

  if (heavy) {
    // fp32 partials, plane-major SoA (coalesced): plane stride PPLANE floats
    float* P = part + ((size_t)(g * 2 + split) * 512 + tid);
#pragma unroll
    for (int nt2 = 0; nt2 < 4; nt2++)
#pragma unroll
      for (int r2 = 0; r2 < 4; r2++) P[(size_t)(nt2 * 4 + r2) * PPLANE] = o_acc[nt2][r2];
    P[(size_t)16 * PPLANE] = m_i;
    P[(size_t)17 * PPLANE] = l_i;
  } else {
    // light epilogue: O[q=q4*4+r][hd=nt2*16+l15] / l[q] -> bf16 [B,S,D]
#pragma unroll
    for (int r2 = 0; r2 < 4; r2++) {
      float lr = __shfl(l_i, q4 * 4 + r2);
      float inv = 1.0f / lr;
      int s_ = q0 + w * 16 + q4 * 4 + r2;
#pragma unroll
      for (int nt2 = 0; nt2 < 4; nt2++)
        O[((size_t)(b * S_ + s_)) * D_ + h * HD_ + nt2 * 16 + l15] = f2b(o_acc[nt2][r2] * inv);
    }
  }
}

// ---------------------------------------------------------------- split-K merge (LSE)
// 256 blocks x 512 threads: one (bh, j) pair each; combines the two heavy partials and
// writes rows q0..q0+127 of head bh for qi=15-j. m/l are uniform across q4-groups (the
// attn shfl_xor(16/32) reductions guarantee it), so the per-row broadcast mirrors the
// R3 epilogue exactly.
__global__ __launch_bounds__(512) void attn_merge_kernel(
    const float* __restrict__ part, unsigned short* __restrict__ O) {
  const int g = blockIdx.x;
  const int bh = g & 31, j = g >> 5;
  const int qi = 15 - j;
  const int b = bh >> 4, h = bh & 15;
  const int tid = threadIdx.x, lane = tid & 63, w = tid >> 6;
  const int l15 = lane & 15, q4 = lane >> 4;

  const float* P0 = part + ((size_t)(g * 2 + 0) * 512 + tid);
  const float* P1 = part + ((size_t)(g * 2 + 1) * 512 + tid);
  float o0[16], o1[16];
#pragma unroll
  for (int i = 0; i < 16; i++) {
    o0[i] = P0[(size_t)i * PPLANE];
    o1[i] = P1[(size_t)i * PPLANE];
  }
  float m0 = P0[(size_t)16 * PPLANE], l0 = P0[(size_t)17 * PPLANE];
  float m1 = P1[(size_t)16 * PPLANE], l1 = P1[(size_t)17 * PPLANE];
  float m  = fmaxf(m0, m1);
  float a0 = __builtin_amdgcn_exp2f(m0 - m);
  float a1 = __builtin_amdgcn_exp2f(m1 - m);
  float l  = l0 * a0 + l1 * a1;

  const int q0 = qi * 128;
#pragma unroll
  for (int r2 = 0; r2 < 4; r2++) {
    float ar0 = __shfl(a0, q4 * 4 + r2);
    float ar1 = __shfl(a1, q4 * 4 + r2);
    float inv = 1.0f / __shfl(l, q4 * 4 + r2);
    int s_ = q0 + w * 16 + q4 * 4 + r2;
#pragma unroll
    for (int nt2 = 0; nt2 < 4; nt2++)
      O[((size_t)(b * S_ + s_)) * D_ + h * HD_ + nt2 * 16 + l15] =
          f2b((o0[nt2 * 4 + r2] * ar0 + o1[nt2 * 4 + r2] * ar1) * inv);
  }
}

// ---------------------------------------------------------------- output GEMM (unchanged)
__global__ __launch_bounds__(512) void out_gemm_kernel(
    const unsigned short* __restrict__ ab, const unsigned short* __restrict__ wot,
    const float* __restrict__ bo, float* __restrict__ out) {
  __shared__ __align__(16) unsigned short smem[6 * 4096];   // 48 KB
  const int tid = threadIdx.x;
  const int lane = tid & 63, wid = tid >> 6;
  const int wm = wid & 1, wn = wid >> 1;
  const int m0 = blockIdx.x * 128, n0 = blockIdx.y * 128;
  const int l15 = lane & 15, q4 = lane >> 4;
  const int srow = tid >> 2, skc = (tid & 3) * 8;

  f32x4 zero = {0.f, 0.f, 0.f, 0.f};
  f32x4 acc[4][2];
#pragma unroll
  for (int mt = 0; mt < 4; mt++)
#pragma unroll
    for (int nt = 0; nt < 2; nt++) acc[mt][nt] = zero;

  const unsigned short* ap = ab  + (size_t)(m0 + srow) * D_ + skc;
  const unsigned short* bp = wot + (size_t)(n0 + srow) * D_ + skc;
  gl_lds16(ap,      smem + tid * 8);
  gl_lds16(bp,      smem + 12288 + tid * 8);
  gl_lds16(ap + 32, smem + 4096 + tid * 8);
  gl_lds16(bp + 32, smem + 12288 + 4096 + tid * 8);

  int bc = 0;
  for (int it = 0; it < 32; it++) {
    if (it < 31) bar_vm2(); else bar_vm0();
    if (it + 2 < 32) {
      int bn_ = bc < 1 ? bc + 2 : bc - 1;
      gl_lds16(ap + (it + 2) * 32, smem + bn_ * 4096 + tid * 8);
      gl_lds16(bp + (it + 2) * 32, smem + 12288 + bn_ * 4096 + tid * 8);
    }
    const unsigned short* Ab = smem + bc * 4096;
    const unsigned short* Bb = smem + 12288 + bc * 4096;
    bf16x8 af[4], bfv[2];
#pragma unroll
    for (int mt = 0; mt < 4; mt++) af[mt]  = *(const bf16x8*)(Ab + (wm * 64 + mt * 16 + l15) * 32 + q4 * 8);
#pragma unroll
    for (int nt = 0; nt < 2; nt++) bfv[nt] = *(const bf16x8*)(Bb + (wn * 32 + nt * 16 + l15) * 32 + q4 * 8);
#pragma unroll
    for (int mt = 0; mt < 4; mt++)
#pragma unroll
      for (int nt = 0; nt < 2; nt++)
        acc[mt][nt] = __builtin_amdgcn_mfma_f32_16x16x32_bf16(af[mt], bfv[nt], acc[mt][nt], 0, 0, 0);
    bc = bc == 2 ? 0 : bc + 1;
  }

#pragma unroll
  for (int nt = 0; nt < 2; nt++) {
    int n = n0 + wn * 32 + nt * 16 + l15;
    float bn = bo[n];
#pragma unroll
    for (int mt = 0; mt < 4; mt++) {
#pragma unroll
      for (int r = 0; r < 4; r++) {
        int m = m0 + wm * 64 + mt * 16 + q4 * 4 + r;
        out[(size_t)m * D_ + n] = acc[mt][nt][r] + bn;
      }
    }
  }
}

// ---------------------------------------------------------------- launch
extern "C" void kernel_launch(void* const* d_in, const int* in_sizes, int n_in,
                              void* d_out, int out_size, void* d_ws, size_t ws_size,
                              hipStream_t stream) {
  const float* x  = (const float*)d_in[0];
  const float* wq = (const float*)d_in[1];
  const float* bq = (const float*)d_in[2];
  const float* wk = (const float*)d_in[3];
  const float* bk = (const float*)d_in[4];
  const float* wv = (const float*)d_in[5];
  const float* bv = (const float*)d_in[6];
  const float* wo = (const float*)d_in[7];
  const float* bo = (const float*)d_in[8];
  float* out = (float*)d_out;

  char* ws = (char*)d_ws;
  unsigned short* xb  = (unsigned short*)(ws);               // 8 MB; reused as attn out
  unsigned short* wqt = (unsigned short*)(ws + (8u  << 20));
  unsigned short* wkt = (unsigned short*)(ws + (10u << 20));
  unsigned short* wvt = (unsigned short*)(ws + (12u << 20));
  unsigned short* wot = (unsigned short*)(ws + (14u << 20));
  unsigned short* qb  = (unsigned short*)(ws + (16u << 20)); // [B,H,S,HD] bf16 (pre-scaled)
  unsigned short* kb  = (unsigned short*)(ws + (24u << 20)); // [B,H,S,HD] bf16
  unsigned short* vtg = (unsigned short*)(ws + (32u << 20)); // [B,H,HD,S] bf16 (transposed V)
  float*          prt = (float*)(ws + (40u << 20));          // split-K partials, 18.9 MB
  unsigned short* ab  = xb;                                  // attention output [B,S,D] bf16

  cvt_all_kernel<<<dim3(32, 32, 5), dim3(32, 8), 0, stream>>>(x, wq, wk, wv, wo, xb, wqt, wkt, wvt, wot);
  qkv_gemm_kernel<<<dim3(32, 8, 3), dim3(512), 0, stream>>>(xb, wqt, wkt, wvt, bq, bk, bv, qb, kb, vtg);
  attn_kernel<<<dim3(768), dim3(512), 0, stream>>>(qb, kb, vtg, ab, prt);
  attn_merge_kernel<<<dim3(256), dim3(512), 0, stream>>>(prt, ab);
  out_gemm_kernel<<<dim3(32, 8), dim3(512), 0, stream>>>(ab, wot, bo, out);
}